// Round 12
// baseline (826.374 us; speedup 1.0000x reference)
//
#include <hip/hip_runtime.h>
#include <math.h>

#define NSEQ  1024
#define CDIM  768
#define NH    12
#define HD    64
#define QS    6291456   // 8*12*1024*64
#define EXPC  0.18033688011112042f   // 0.125 * log2(e)
#define GRIDB 768       // 3 blocks/CU; LDS+VGPR allow 4 -> co-residency guaranteed

// workspace layout (shorts): xb/ab alias | wq | wp | qkvb | counters
#define WS_XB    0
#define WS_WQ    6291456              // 8192*768
#define WS_WP    (WS_WQ + 1769472)    // +3*768*768
#define WS_QKVB  (WS_WP + 589824)     // +768*768
#define WS_CTR   (WS_QKVB + 3 * QS)   // counters (uint bar, uint ticket)

typedef __bf16 bf16x8 __attribute__((ext_vector_type(8)));
typedef float  f32x4  __attribute__((ext_vector_type(4)));

__device__ __forceinline__ unsigned short f2bf(float f) {
    union { float f; unsigned u; } v; v.f = f;
    unsigned r = v.u + 0x7FFFu + ((v.u >> 16) & 1u);  // RNE
    return (unsigned short)(r >> 16);
}

__device__ __forceinline__ unsigned pk_hi16(unsigned a, unsigned b) {
    return __builtin_amdgcn_perm(b, a, 0x07060302u);
}
__device__ __forceinline__ uint2 pack4bf_trunc(float p0, float p1, float p2, float p3) {
    return make_uint2(pk_hi16(__float_as_uint(p0), __float_as_uint(p1)),
                      pk_hi16(__float_as_uint(p2), __float_as_uint(p3)));
}

__device__ __forceinline__ void gld_lds16(const unsigned short* g, unsigned short* l) {
    __builtin_amdgcn_global_load_lds(
        (const __attribute__((address_space(1))) void*)g,
        (__attribute__((address_space(3))) void*)l, 16, 0, 0);
}

// Device-scope grid barrier (G16 pattern): release-add to arrive, acquire-load
// spin; agent scope -> cross-XCD L2 writeback/invalidate. Timeout makes any
// failure a visible wrong answer instead of a hang.
__device__ __forceinline__ void grid_bar(unsigned* bar, unsigned target) {
    __syncthreads();
    if (threadIdx.x == 0) {
        __threadfence();
        __hip_atomic_fetch_add(bar, 1u, __ATOMIC_RELEASE, __HIP_MEMORY_SCOPE_AGENT);
        long long t0 = __builtin_amdgcn_s_memrealtime();
        while (__hip_atomic_load(bar, __ATOMIC_ACQUIRE, __HIP_MEMORY_SCOPE_AGENT) < target) {
            __builtin_amdgcn_s_sleep(8);
            if (__builtin_amdgcn_s_memrealtime() - t0 > 50000000LL) break;  // ~0.5s
        }
    }
    __syncthreads();
}

// ---------------------------------------------------------------------------
// GEMM tile (R10-proven): 128x128, BK=32, dbuf LDS in smem[0..16384).
// MODE 0: fp32 out. MODE 1: bf16 scatter to [3][B][NH][N][HD], Q-third
// pre-scaled by EXPC; LDS-transpose epilogue reuses smem.
// ---------------------------------------------------------------------------
template <int MODE>
__device__ __forceinline__ void gemm_tile(const int m0, const int n0,
                                          const unsigned short* __restrict__ A,
                                          const unsigned short* __restrict__ Bw,
                                          const float* __restrict__ bias,
                                          void* __restrict__ outp,
                                          const int N, const int K,
                                          unsigned short* smem) {
    const int tid = threadIdx.x;
    const int wave = tid >> 6, lane = tid & 63;
    const int row16 = lane & 15, quad = lane >> 4;
    const int wm = (wave >> 1) * 64, wn = (wave & 1) * 64;

    const int srow0 = (tid * 8) >> 5,         scol0 = (tid * 8) & 31;
    const int srow1 = ((tid + 256) * 8) >> 5, scol1 = ((tid + 256) * 8) & 31;

    __syncthreads();   // smem handoff from previous stage/tile

    f32x4 acc[4][4];
#pragma unroll
    for (int i = 0; i < 4; ++i)
#pragma unroll
        for (int j = 0; j < 4; ++j) acc[i][j] = (f32x4){0.f, 0.f, 0.f, 0.f};

    gld_lds16(&A[(size_t)(m0 + srow0) * K + scol0], &smem[wave * 512]);
    gld_lds16(&A[(size_t)(m0 + srow1) * K + scol1], &smem[2048 + wave * 512]);
    gld_lds16(&Bw[(size_t)(n0 + srow0) * K + scol0], &smem[8192 + wave * 512]);
    gld_lds16(&Bw[(size_t)(n0 + srow1) * K + scol1], &smem[8192 + 2048 + wave * 512]);

    const int nk = K / 32;
    for (int ki = 0; ki < nk; ++ki) {
        const int co = (ki & 1) * 4096;
        const int no = 4096 - co;
        __syncthreads();
        if (ki + 1 < nk) {
            const int k0 = (ki + 1) * 32;
            gld_lds16(&A[(size_t)(m0 + srow0) * K + k0 + scol0], &smem[no + wave * 512]);
            gld_lds16(&A[(size_t)(m0 + srow1) * K + k0 + scol1], &smem[no + 2048 + wave * 512]);
            gld_lds16(&Bw[(size_t)(n0 + srow0) * K + k0 + scol0], &smem[8192 + no + wave * 512]);
            gld_lds16(&Bw[(size_t)(n0 + srow1) * K + k0 + scol1], &smem[8192 + no + 2048 + wave * 512]);
        }
        bf16x8 af[4], bfr[4];
#pragma unroll
        for (int mt = 0; mt < 4; ++mt)
            af[mt] = *(const bf16x8*)&smem[co + (wm + mt * 16 + row16) * 32 + quad * 8];
#pragma unroll
        for (int nt = 0; nt < 4; ++nt)
            bfr[nt] = *(const bf16x8*)&smem[8192 + co + (wn + nt * 16 + row16) * 32 + quad * 8];
#pragma unroll
        for (int mt = 0; mt < 4; ++mt)
#pragma unroll
            for (int nt = 0; nt < 4; ++nt)
                acc[mt][nt] = __builtin_amdgcn_mfma_f32_16x16x32_bf16(af[mt], bfr[nt], acc[mt][nt], 0, 0, 0);
    }

    if (MODE == 0) {
        float bias4[4];
#pragma unroll
        for (int nt = 0; nt < 4; ++nt) bias4[nt] = bias[n0 + wn + nt * 16 + row16];
#pragma unroll
        for (int mt = 0; mt < 4; ++mt)
#pragma unroll
            for (int nt = 0; nt < 4; ++nt)
#pragma unroll
                for (int r = 0; r < 4; ++r) {
                    int grow = m0 + wm + mt * 16 + quad * 4 + r;
                    int gcol = n0 + wn + nt * 16 + row16;
                    ((float*)outp)[(size_t)grow * N + gcol] = acc[mt][nt][r] + bias4[nt];
                }
    } else {
        float scv[4], bsv[4];
#pragma unroll
        for (int nt = 0; nt < 4; ++nt) {
            int gc = n0 + wn + nt * 16 + row16;
            float sc = (gc < CDIM) ? EXPC : 1.0f;
            scv[nt] = sc;
            bsv[nt] = bias[gc] * sc;
        }
        unsigned short* qkvb = (unsigned short*)outp;
        __syncthreads();
#pragma unroll
        for (int mt = 0; mt < 4; ++mt)
#pragma unroll
            for (int nt = 0; nt < 4; ++nt)
#pragma unroll
                for (int r = 0; r < 4; ++r)
                    smem[(wm + mt * 16 + quad * 4 + r) * 128 + wn + nt * 16 + row16] =
                        f2bf(fmaf(acc[mt][nt][r], scv[nt], bsv[nt]));
        __syncthreads();
#pragma unroll
        for (int i = 0; i < 8; ++i) {
            int u4 = i * 256 + tid;
            int row = u4 >> 4;
            int c8 = u4 & 15;
            int grow = m0 + row;
            int gcol = n0 + c8 * 8;
            int t = gcol / CDIM;
            int rr = gcol - t * CDIM;
            int h = rr >> 6, d = rr & 63;
            int b = grow >> 10, n = grow & 1023;
            *(uint4*)&qkvb[(size_t)t * QS + ((((size_t)b * NH + h) << 10) + n) * 64 + d] =
                *(const uint4*)&smem[row * 128 + c8 * 8];
        }
    }
}

// ---------------------------------------------------------------------------
// Flash attention body (R10-proven). smem: Ks[0..4608) Vt[4608..9216)
// Ps[9216..18432). Q pre-scaled by EXPC -> p = exp2(s). S^T = K·Q^T,
// packed b64 P-stores, K/V register prefetch, XCD swizzle.
// ---------------------------------------------------------------------------
__device__ __forceinline__ void attn_body(const int bid,
                                          const unsigned short* __restrict__ qkv,
                                          unsigned short* __restrict__ abuf,
                                          unsigned short* smem) {
    unsigned short* Ks = smem;
    unsigned short* Vt = smem + 4608;
    unsigned short* Psb = smem + 9216;

    const int tid = threadIdx.x;
    const int wave = tid >> 6, lane = tid & 63;
    const int row16 = lane & 15, quad = lane >> 4;
    const int xcd = bid & 7;
    const int local = bid >> 3;          // 0..95
    const int bh = xcd * 12 + (local >> 3);
    const int qt = local & 7;
    unsigned short* Psw = Psb + wave * 2304;

    const unsigned short* Qg = qkv + (size_t)bh * NSEQ * HD + (size_t)qt * 128 * HD;
    const unsigned short* Kg = qkv + (size_t)QS + (size_t)bh * NSEQ * HD;
    const unsigned short* Vg = qkv + (size_t)2 * QS + (size_t)bh * NSEQ * HD;

    bf16x8 aq[2][2];
#pragma unroll
    for (int mt = 0; mt < 2; ++mt)
#pragma unroll
        for (int kst = 0; kst < 2; ++kst)
            aq[mt][kst] = *(const bf16x8*)&Qg[(size_t)(wave * 32 + mt * 16 + row16) * 64 +
                                              kst * 32 + quad * 8];

    f32x4 o[2][4];
    float l_i[2] = {0.f, 0.f};
#pragma unroll
    for (int mt = 0; mt < 2; ++mt)
#pragma unroll
        for (int j = 0; j < 4; ++j) o[mt][j] = (f32x4){0.f, 0.f, 0.f, 0.f};

    const int krow0 = (tid * 8) >> 6,  kcol0 = (tid * 8) & 63;
    const int krow1 = ((tid + 256) * 8) >> 6, kcol1 = ((tid + 256) * 8) & 63;
    const int kpair = tid & 31;
    const int colc = tid >> 5;

    uint4 ka = *(const uint4*)&Kg[(size_t)krow0 * 64 + kcol0];
    uint4 kb = *(const uint4*)&Kg[(size_t)krow1 * 64 + kcol1];
    uint4 va = *(const uint4*)&Vg[(size_t)(2 * kpair) * 64 + colc * 8];
    uint4 vb = *(const uint4*)&Vg[(size_t)(2 * kpair + 1) * 64 + colc * 8];

    for (int kt = 0; kt < 16; ++kt) {
        __syncthreads();
        *(uint4*)&Ks[krow0 * 72 + kcol0] = ka;
        *(uint4*)&Ks[krow1 * 72 + kcol1] = kb;
        {
            const unsigned* pa = (const unsigned*)&va;
            const unsigned* pb = (const unsigned*)&vb;
            unsigned int* vt32 = (unsigned int*)Vt;
#pragma unroll
            for (int jj = 0; jj < 4; ++jj) {
                vt32[(colc * 8 + 2 * jj)     * 36 + kpair] =
                    __builtin_amdgcn_perm(pb[jj], pa[jj], 0x05040100u);
                vt32[(colc * 8 + 2 * jj + 1) * 36 + kpair] =
                    __builtin_amdgcn_perm(pb[jj], pa[jj], 0x07060302u);
            }
        }
        __syncthreads();

        if (kt < 15) {
            const unsigned short* kn = Kg + (size_t)(kt + 1) * 64 * 64;
            const unsigned short* vn = Vg + (size_t)(kt + 1) * 64 * 64;
            ka = *(const uint4*)&kn[(size_t)krow0 * 64 + kcol0];
            kb = *(const uint4*)&kn[(size_t)krow1 * 64 + kcol1];
            va = *(const uint4*)&vn[(size_t)(2 * kpair) * 64 + colc * 8];
            vb = *(const uint4*)&vn[(size_t)(2 * kpair + 1) * 64 + colc * 8];
        }

        f32x4 st[4][2];
#pragma unroll
        for (int nt = 0; nt < 4; ++nt)
#pragma unroll
            for (int mt = 0; mt < 2; ++mt) st[nt][mt] = (f32x4){0.f, 0.f, 0.f, 0.f};
#pragma unroll
        for (int kst = 0; kst < 2; ++kst) {
            bf16x8 ak[4];
#pragma unroll
            for (int nt = 0; nt < 4; ++nt)
                ak[nt] = *(const bf16x8*)&Ks[(nt * 16 + row16) * 72 + kst * 32 + quad * 8];
#pragma unroll
            for (int nt = 0; nt < 4; ++nt)
#pragma unroll
                for (int mt = 0; mt < 2; ++mt)
                    st[nt][mt] = __builtin_amdgcn_mfma_f32_16x16x32_bf16(ak[nt], aq[mt][kst], st[nt][mt], 0, 0, 0);
        }

#pragma unroll
        for (int mt = 0; mt < 2; ++mt)
#pragma unroll
            for (int nt = 0; nt < 4; ++nt) {
                float p0 = __builtin_amdgcn_exp2f(st[nt][mt][0]);
                float p1 = __builtin_amdgcn_exp2f(st[nt][mt][1]);
                float p2 = __builtin_amdgcn_exp2f(st[nt][mt][2]);
                float p3 = __builtin_amdgcn_exp2f(st[nt][mt][3]);
                l_i[mt] += (p0 + p1) + (p2 + p3);
                *(uint2*)&Psw[(mt * 16 + row16) * 72 + nt * 16 + quad * 4] =
                    pack4bf_trunc(p0, p1, p2, p3);
            }

#pragma unroll
        for (int kst = 0; kst < 2; ++kst) {
            bf16x8 ap[2], bv[4];
#pragma unroll
            for (int mt = 0; mt < 2; ++mt)
                ap[mt] = *(const bf16x8*)&Psw[(mt * 16 + row16) * 72 + kst * 32 + quad * 8];
#pragma unroll
            for (int dt = 0; dt < 4; ++dt)
                bv[dt] = *(const bf16x8*)&Vt[(dt * 16 + row16) * 72 + kst * 32 + quad * 8];
#pragma unroll
            for (int mt = 0; mt < 2; ++mt)
#pragma unroll
                for (int dt = 0; dt < 4; ++dt)
                    o[mt][dt] = __builtin_amdgcn_mfma_f32_16x16x32_bf16(ap[mt], bv[dt], o[mt][dt], 0, 0, 0);
        }
    }

    const int b = bh / NH, h = bh - b * NH;
#pragma unroll
    for (int mt = 0; mt < 2; ++mt) {
        float l = l_i[mt];
        l += __shfl_xor(l, 16);
        l += __shfl_xor(l, 32);
#pragma unroll
        for (int r = 0; r < 4; ++r) {
            float inv = 1.f / __shfl(l, quad * 4 + r);
            int n = qt * 128 + wave * 32 + mt * 16 + quad * 4 + r;
            size_t base = ((size_t)(b * NSEQ + n)) * CDIM + h * HD;
#pragma unroll
            for (int dt = 0; dt < 4; ++dt)
                abuf[base + dt * 16 + row16] = f2bf(o[mt][dt][r] * inv);
        }
    }
}

// ---------------------------------------------------------------------------
// Fused kernel, regular launch + manual grid barrier. Grid 768 = 3 blocks/CU
// (theoretical capacity 4: LDS 36.9KB, VGPR<=128 via launch_bounds) -> all
// blocks co-resident. cvt -> bar -> qkv (ticketed) -> bar -> attn -> bar -> proj.
// ---------------------------------------------------------------------------
__global__ __launch_bounds__(256, 4) void fused_all(const float* __restrict__ x,
                                                    const float* __restrict__ qkv_w,
                                                    const float* __restrict__ qkv_b,
                                                    const float* __restrict__ proj_w,
                                                    const float* __restrict__ proj_b,
                                                    float* __restrict__ out,
                                                    unsigned short* __restrict__ ws) {
    __shared__ unsigned short smem[18432];   // union: gemm 32K / attn 36.9K
    __shared__ unsigned tsh;

    unsigned short* xb   = ws + WS_XB;
    unsigned short* wq   = ws + WS_WQ;
    unsigned short* wp   = ws + WS_WP;
    unsigned short* qkvb = ws + WS_QKVB;
    unsigned short* ab   = xb;               // aliases xb (dead after stage 1)
    unsigned* bar = (unsigned*)(ws + WS_CTR);
    unsigned* tk  = bar + 1;

    const int tid = threadIdx.x;
    const int bid = blockIdx.x;

    // ---- stage 0: fp32 -> bf16 (11 exact grid-stride float4 iters) ----
    {
        const int n0 = 8192 * CDIM, n1 = 3 * CDIM * CDIM;
        int tg = bid * 256 + tid;
#pragma unroll
        for (int it = 0; it < 11; ++it) {
            int i = (tg + it * GRIDB * 256) * 4;
            const float* s; unsigned short* d; int off;
            if (i < n0)           { s = x;      d = xb; off = i; }
            else if (i < n0 + n1) { s = qkv_w;  d = wq; off = i - n0; }
            else                  { s = proj_w; d = wp; off = i - n0 - n1; }
            float4 v = *(const float4*)(s + off);
            ushort4 o;
            o.x = f2bf(v.x); o.y = f2bf(v.y); o.z = f2bf(v.z); o.w = f2bf(v.w);
            *(ushort4*)(d + off) = o;
        }
    }
    grid_bar(bar, GRIDB);

    // ---- stage 1: QKV GEMM, 1152 tiles via atomic work ticket ----
    for (;;) {
        __syncthreads();
        if (tid == 0) tsh = atomicAdd(tk, 1u);
        __syncthreads();
        unsigned t = tsh;
        if (t >= 1152) break;
        gemm_tile<1>((t & 63) * 128, (t >> 6) * 128, xb, wq, qkv_b, qkvb,
                     3 * CDIM, CDIM, smem);
    }
    grid_bar(bar, 2 * GRIDB);

    // ---- stage 2: attention (768 blocks exact) ----
    attn_body(bid, qkvb, ab, smem);
    grid_bar(bar, 3 * GRIDB);

    // ---- stage 3: proj GEMM, 384 tiles ----
    if (bid < 384)
        gemm_tile<0>((bid & 63) * 128, (bid >> 6) * 128, ab, wp, proj_b, out,
                     CDIM, CDIM, smem);
}

// ---------------------------------------------------------------------------
extern "C" void kernel_launch(void* const* d_in, const int* in_sizes, int n_in,
                              void* d_out, int out_size, void* d_ws, size_t ws_size,
                              hipStream_t stream) {
    const float* x      = (const float*)d_in[0];  // [8,1024,768]
    const float* qkv_w  = (const float*)d_in[1];  // [2304,768]
    const float* qkv_b  = (const float*)d_in[2];  // [2304]
    const float* proj_w = (const float*)d_in[3];  // [768,768]
    const float* proj_b = (const float*)d_in[4];  // [768]
    float* out = (float*)d_out;                   // [8,1024,768]
    unsigned short* ws = (unsigned short*)d_ws;

    // zero the barrier + ticket counters (workspace is poisoned each call)
    hipMemsetAsync((char*)d_ws + (size_t)WS_CTR * 2, 0, 64, stream);

    fused_all<<<dim3(GRIDB), dim3(256), 0, stream>>>(x, qkv_w, qkv_b,
                                                     proj_w, proj_b, out, ws);
}

// Round 13
// 187.447 us; speedup vs baseline: 4.4086x; 4.4086x over previous
//
#include <hip/hip_runtime.h>
#include <math.h>

#define NSEQ  1024
#define CDIM  768
#define NH    12
#define HD    64
#define QS    6291456   // 8*12*1024*64
#define EXPC  0.18033688011112042f   // 0.125 * log2(e)

typedef __bf16 bf16x8 __attribute__((ext_vector_type(8)));
typedef float  f32x4  __attribute__((ext_vector_type(4)));

__device__ __forceinline__ unsigned short f2bf(float f) {
    union { float f; unsigned u; } v; v.f = f;
    unsigned r = v.u + 0x7FFFu + ((v.u >> 16) & 1u);  // RNE
    return (unsigned short)(r >> 16);
}

__device__ __forceinline__ unsigned pk_hi16(unsigned a, unsigned b) {
    return __builtin_amdgcn_perm(b, a, 0x07060302u);
}
__device__ __forceinline__ uint2 pack4bf_trunc(float p0, float p1, float p2, float p3) {
    return make_uint2(pk_hi16(__float_as_uint(p0), __float_as_uint(p1)),
                      pk_hi16(__float_as_uint(p2), __float_as_uint(p3)));
}

__device__ __forceinline__ void gld_lds16(const unsigned short* g, unsigned short* l) {
    __builtin_amdgcn_global_load_lds(
        (const __attribute__((address_space(1))) void*)g,
        (__attribute__((address_space(3))) void*)l, 16, 0, 0);
}

// ---------------------------------------------------------------------------
__global__ __launch_bounds__(256) void cvt_all(const float* __restrict__ x,
                                               const float* __restrict__ w1,
                                               const float* __restrict__ w2,
                                               unsigned short* __restrict__ xb,
                                               unsigned short* __restrict__ w1b,
                                               unsigned short* __restrict__ w2b,
                                               int n0, int n1, int n2) {
    int i = (blockIdx.x * 256 + threadIdx.x) * 4;
    const float* s; unsigned short* d; int off;
    if (i < n0)           { s = x;  d = xb;  off = i; }
    else if (i < n0 + n1) { s = w1; d = w1b; off = i - n0; }
    else if (i < n0 + n1 + n2) { s = w2; d = w2b; off = i - n0 - n1; }
    else return;
    float4 v = *(const float4*)(s + off);
    ushort4 o;
    o.x = f2bf(v.x); o.y = f2bf(v.y); o.z = f2bf(v.z); o.w = f2bf(v.w);
    *(ushort4*)(d + off) = o;
}

// ---------------------------------------------------------------------------
// bf16 MFMA GEMM (R10-proven): 128x128 tile, BK=32, dbuf LDS (one barrier per
// iter), 4 waves x 64x64. MODE 0: fp32 out. MODE 1: bf16 scatter into
// [3][B][NH][N][HD]; Q-third pre-scaled by EXPC.
// ---------------------------------------------------------------------------
template <int MODE>
__global__ __launch_bounds__(256) void mfma_gemm_bt(const unsigned short* __restrict__ A,
                                                    const unsigned short* __restrict__ Bw,
                                                    const float* __restrict__ bias,
                                                    void* __restrict__ outp,
                                                    int M, int N, int K) {
    __shared__ unsigned short smem[4 * 128 * 32];   // As0|As1|Bs0|Bs1 = 32 KB

    const int tid = threadIdx.x;
    const int wave = tid >> 6, lane = tid & 63;
    const int row16 = lane & 15, quad = lane >> 4;
    const int wm = (wave >> 1) * 64, wn = (wave & 1) * 64;
    const int m0 = blockIdx.x * 128, n0 = blockIdx.y * 128;

    const int srow0 = (tid * 8) >> 5,         scol0 = (tid * 8) & 31;
    const int srow1 = ((tid + 256) * 8) >> 5, scol1 = ((tid + 256) * 8) & 31;

    f32x4 acc[4][4];
#pragma unroll
    for (int i = 0; i < 4; ++i)
#pragma unroll
        for (int j = 0; j < 4; ++j) acc[i][j] = (f32x4){0.f, 0.f, 0.f, 0.f};

    gld_lds16(&A[(size_t)(m0 + srow0) * K + scol0], &smem[wave * 512]);
    gld_lds16(&A[(size_t)(m0 + srow1) * K + scol1], &smem[2048 + wave * 512]);
    gld_lds16(&Bw[(size_t)(n0 + srow0) * K + scol0], &smem[8192 + wave * 512]);
    gld_lds16(&Bw[(size_t)(n0 + srow1) * K + scol1], &smem[8192 + 2048 + wave * 512]);

    const int nk = K / 32;
    for (int ki = 0; ki < nk; ++ki) {
        const int co = (ki & 1) * 4096;
        const int no = 4096 - co;
        __syncthreads();
        if (ki + 1 < nk) {
            const int k0 = (ki + 1) * 32;
            gld_lds16(&A[(size_t)(m0 + srow0) * K + k0 + scol0], &smem[no + wave * 512]);
            gld_lds16(&A[(size_t)(m0 + srow1) * K + k0 + scol1], &smem[no + 2048 + wave * 512]);
            gld_lds16(&Bw[(size_t)(n0 + srow0) * K + k0 + scol0], &smem[8192 + no + wave * 512]);
            gld_lds16(&Bw[(size_t)(n0 + srow1) * K + k0 + scol1], &smem[8192 + no + 2048 + wave * 512]);
        }
        bf16x8 af[4], bfr[4];
#pragma unroll
        for (int mt = 0; mt < 4; ++mt)
            af[mt] = *(const bf16x8*)&smem[co + (wm + mt * 16 + row16) * 32 + quad * 8];
#pragma unroll
        for (int nt = 0; nt < 4; ++nt)
            bfr[nt] = *(const bf16x8*)&smem[8192 + co + (wn + nt * 16 + row16) * 32 + quad * 8];
#pragma unroll
        for (int mt = 0; mt < 4; ++mt)
#pragma unroll
            for (int nt = 0; nt < 4; ++nt)
                acc[mt][nt] = __builtin_amdgcn_mfma_f32_16x16x32_bf16(af[mt], bfr[nt], acc[mt][nt], 0, 0, 0);
    }

    if (MODE == 0) {
        float bias4[4];
#pragma unroll
        for (int nt = 0; nt < 4; ++nt) bias4[nt] = bias[n0 + wn + nt * 16 + row16];
#pragma unroll
        for (int mt = 0; mt < 4; ++mt)
#pragma unroll
            for (int nt = 0; nt < 4; ++nt)
#pragma unroll
                for (int r = 0; r < 4; ++r) {
                    int grow = m0 + wm + mt * 16 + quad * 4 + r;
                    int gcol = n0 + wn + nt * 16 + row16;
                    ((float*)outp)[(size_t)grow * N + gcol] = acc[mt][nt][r] + bias4[nt];
                }
    } else {
        float scv[4], bsv[4];
#pragma unroll
        for (int nt = 0; nt < 4; ++nt) {
            int gc = n0 + wn + nt * 16 + row16;
            float sc = (gc < CDIM) ? EXPC : 1.0f;
            scv[nt] = sc;
            bsv[nt] = bias[gc] * sc;
        }
        unsigned short* qkvb = (unsigned short*)outp;
        __syncthreads();
#pragma unroll
        for (int mt = 0; mt < 4; ++mt)
#pragma unroll
            for (int nt = 0; nt < 4; ++nt)
#pragma unroll
                for (int r = 0; r < 4; ++r)
                    smem[(wm + mt * 16 + quad * 4 + r) * 128 + wn + nt * 16 + row16] =
                        f2bf(fmaf(acc[mt][nt][r], scv[nt], bsv[nt]));
        __syncthreads();
#pragma unroll
        for (int i = 0; i < 8; ++i) {
            int u4 = i * 256 + tid;
            int row = u4 >> 4;
            int c8 = u4 & 15;
            int grow = m0 + row;
            int gcol = n0 + c8 * 8;
            int t = gcol / CDIM;
            int rr = gcol - t * CDIM;
            int h = rr >> 6, d = rr & 63;
            int b = grow >> 10, n = grow & 1023;
            *(uint4*)&qkvb[(size_t)t * QS + ((((size_t)b * NH + h) << 10) + n) * 64 + d] =
                *(const uint4*)&smem[row * 128 + c8 * 8];
        }
    }
}

// ---------------------------------------------------------------------------
// Flash attention, Q-TILE 256 (wave = 64 q-rows): per k-tile per wave,
// 64 MFMA vs 24 ds_read_b128 (ak/bv amortized over 4 mt) — LDS-issue per
// MFMA drops 7.5 -> 4.5 cyc. LDS 54KB -> 2 blocks/CU; VGPR budget free at
// 2 waves/SIMD. Q pre-scaled by EXPC -> p = exp2(s). S^T = K·Q^T with
// packed b64 P-stores; K/V register prefetch; XCD swizzle (12 bh/XCD).
// ---------------------------------------------------------------------------
__global__ __launch_bounds__(256, 2) void attn_mfma(const unsigned short* __restrict__ qkv,
                                                    unsigned short* __restrict__ abuf) {
    __shared__ unsigned short Ks[64 * 72];
    __shared__ unsigned short Vt[64 * 72];          // Vt[d][key]
    __shared__ unsigned short Ps[4][64 * 72];       // per-wave P, 64 q-rows

    const int tid = threadIdx.x;
    const int wave = tid >> 6, lane = tid & 63;
    const int row16 = lane & 15, quad = lane >> 4;
    const int bid = blockIdx.x;          // 0..383
    const int xcd = bid & 7;
    const int local = bid >> 3;          // 0..47
    const int bh = xcd * 12 + (local >> 2);
    const int qt = local & 3;

    const unsigned short* Qg = qkv + (size_t)bh * NSEQ * HD + (size_t)qt * 256 * HD;
    const unsigned short* Kg = qkv + (size_t)QS + (size_t)bh * NSEQ * HD;
    const unsigned short* Vg = qkv + (size_t)2 * QS + (size_t)bh * NSEQ * HD;

    // Q fragments in registers: wave owns q-rows [wave*64, wave*64+64)
    bf16x8 aq[4][2];
#pragma unroll
    for (int mt = 0; mt < 4; ++mt)
#pragma unroll
        for (int kst = 0; kst < 2; ++kst)
            aq[mt][kst] = *(const bf16x8*)&Qg[(size_t)(wave * 64 + mt * 16 + row16) * 64 +
                                              kst * 32 + quad * 8];

    f32x4 o[4][4];
    float l_i[4] = {0.f, 0.f, 0.f, 0.f};
#pragma unroll
    for (int mt = 0; mt < 4; ++mt)
#pragma unroll
        for (int j = 0; j < 4; ++j) o[mt][j] = (f32x4){0.f, 0.f, 0.f, 0.f};

    const int krow0 = (tid * 8) >> 6,  kcol0 = (tid * 8) & 63;
    const int krow1 = ((tid + 256) * 8) >> 6, kcol1 = ((tid + 256) * 8) & 63;
    const int kpair = tid & 31;
    const int colc = tid >> 5;

    uint4 ka = *(const uint4*)&Kg[(size_t)krow0 * 64 + kcol0];
    uint4 kb = *(const uint4*)&Kg[(size_t)krow1 * 64 + kcol1];
    uint4 va = *(const uint4*)&Vg[(size_t)(2 * kpair) * 64 + colc * 8];
    uint4 vb = *(const uint4*)&Vg[(size_t)(2 * kpair + 1) * 64 + colc * 8];

    unsigned short* Psw = &Ps[wave][0];

    for (int kt = 0; kt < 16; ++kt) {
        __syncthreads();   // WAR: prior tile's Ks/Vt reads complete
        *(uint4*)&Ks[krow0 * 72 + kcol0] = ka;
        *(uint4*)&Ks[krow1 * 72 + kcol1] = kb;
        {
            const unsigned* pa = (const unsigned*)&va;
            const unsigned* pb = (const unsigned*)&vb;
            unsigned int* vt32 = (unsigned int*)Vt;
#pragma unroll
            for (int jj = 0; jj < 4; ++jj) {
                vt32[(colc * 8 + 2 * jj)     * 36 + kpair] =
                    __builtin_amdgcn_perm(pb[jj], pa[jj], 0x05040100u);
                vt32[(colc * 8 + 2 * jj + 1) * 36 + kpair] =
                    __builtin_amdgcn_perm(pb[jj], pa[jj], 0x07060302u);
            }
        }
        __syncthreads();

        if (kt < 15) {
            const unsigned short* kn = Kg + (size_t)(kt + 1) * 64 * 64;
            const unsigned short* vn = Vg + (size_t)(kt + 1) * 64 * 64;
            ka = *(const uint4*)&kn[(size_t)krow0 * 64 + kcol0];
            kb = *(const uint4*)&kn[(size_t)krow1 * 64 + kcol1];
            va = *(const uint4*)&vn[(size_t)(2 * kpair) * 64 + colc * 8];
            vb = *(const uint4*)&vn[(size_t)(2 * kpair + 1) * 64 + colc * 8];
        }

        // K fragments read ONCE, reused across all 4 mt
        bf16x8 ak[2][4];
#pragma unroll
        for (int kst = 0; kst < 2; ++kst)
#pragma unroll
            for (int nt = 0; nt < 4; ++nt)
                ak[kst][nt] = *(const bf16x8*)&Ks[(nt * 16 + row16) * 72 + kst * 32 + quad * 8];

        // S^T = K Q^T per mt; softmax numerator; packed b64 P-store
#pragma unroll
        for (int mt = 0; mt < 4; ++mt) {
            f32x4 st[4];
#pragma unroll
            for (int nt = 0; nt < 4; ++nt) st[nt] = (f32x4){0.f, 0.f, 0.f, 0.f};
#pragma unroll
            for (int kst = 0; kst < 2; ++kst)
#pragma unroll
                for (int nt = 0; nt < 4; ++nt)
                    st[nt] = __builtin_amdgcn_mfma_f32_16x16x32_bf16(ak[kst][nt], aq[mt][kst], st[nt], 0, 0, 0);
#pragma unroll
            for (int nt = 0; nt < 4; ++nt) {
                float p0 = __builtin_amdgcn_exp2f(st[nt][0]);
                float p1 = __builtin_amdgcn_exp2f(st[nt][1]);
                float p2 = __builtin_amdgcn_exp2f(st[nt][2]);
                float p3 = __builtin_amdgcn_exp2f(st[nt][3]);
                l_i[mt] += (p0 + p1) + (p2 + p3);
                *(uint2*)&Psw[(mt * 16 + row16) * 72 + nt * 16 + quad * 4] =
                    pack4bf_trunc(p0, p1, p2, p3);
            }
        }

        // O += P V  (V fragments read once per kst, reused across 4 mt)
#pragma unroll
        for (int kst = 0; kst < 2; ++kst) {
            bf16x8 bv[4], ap[4];
#pragma unroll
            for (int dt = 0; dt < 4; ++dt)
                bv[dt] = *(const bf16x8*)&Vt[(dt * 16 + row16) * 72 + kst * 32 + quad * 8];
#pragma unroll
            for (int mt = 0; mt < 4; ++mt)
                ap[mt] = *(const bf16x8*)&Psw[(mt * 16 + row16) * 72 + kst * 32 + quad * 8];
#pragma unroll
            for (int mt = 0; mt < 4; ++mt)
#pragma unroll
                for (int dt = 0; dt < 4; ++dt)
                    o[mt][dt] = __builtin_amdgcn_mfma_f32_16x16x32_bf16(ap[mt], bv[dt], o[mt][dt], 0, 0, 0);
        }
    }

    const int b = bh / NH, h = bh - b * NH;
#pragma unroll
    for (int mt = 0; mt < 4; ++mt) {
        float l = l_i[mt];
        l += __shfl_xor(l, 16);
        l += __shfl_xor(l, 32);
#pragma unroll
        for (int r = 0; r < 4; ++r) {
            float inv = 1.f / __shfl(l, quad * 4 + r);
            int n = qt * 256 + wave * 64 + mt * 16 + quad * 4 + r;
            size_t base = ((size_t)(b * NSEQ + n)) * CDIM + h * HD;
#pragma unroll
            for (int dt = 0; dt < 4; ++dt)
                abuf[base + dt * 16 + row16] = f2bf(o[mt][dt][r] * inv);
        }
    }
}

// ---------------------------------------------------------------------------
extern "C" void kernel_launch(void* const* d_in, const int* in_sizes, int n_in,
                              void* d_out, int out_size, void* d_ws, size_t ws_size,
                              hipStream_t stream) {
    const float* x      = (const float*)d_in[0];  // [8,1024,768]
    const float* qkv_w  = (const float*)d_in[1];  // [2304,768]
    const float* qkv_b  = (const float*)d_in[2];  // [2304]
    const float* proj_w = (const float*)d_in[3];  // [768,768]
    const float* proj_b = (const float*)d_in[4];  // [768]
    float* out = (float*)d_out;                   // [8,1024,768]

    const int M = 8 * NSEQ;  // 8192
    unsigned short* ws = (unsigned short*)d_ws;
    unsigned short* xb   = ws;                             // 8192*768
    unsigned short* wq   = xb + (size_t)M * CDIM;          // 2304*768
    unsigned short* wp   = wq + (size_t)3 * CDIM * CDIM;   // 768*768
    unsigned short* qkvb = wp + (size_t)CDIM * CDIM;       // 3*QS
    unsigned short* ab   = qkvb + (size_t)3 * QS;          // 8192*768

    const int nx = M * CDIM, nq = 3 * CDIM * CDIM, np = CDIM * CDIM;
    cvt_all<<<(nx + nq + np) / 1024, 256, 0, stream>>>(x, qkv_w, proj_w, xb, wq, wp,
                                                       nx, nq, np);

    mfma_gemm_bt<1><<<dim3(M / 128, (3 * CDIM) / 128), 256, 0, stream>>>(
        xb, wq, qkv_b, qkvb, M, 3 * CDIM, CDIM);

    attn_mfma<<<dim3(8 * NH * (NSEQ / 256)), 256, 0, stream>>>(qkvb, ab);

    mfma_gemm_bt<0><<<dim3(M / 128, CDIM / 128), 256, 0, stream>>>(
        ab, wp, proj_b, out, M, CDIM, CDIM);
}